// Round 5
// baseline (412.551 us; speedup 1.0000x reference)
//
#include <hip/hip_runtime.h>
#include <hip/hip_bf16.h>
#include <stdint.h>

// B=128, T=256, C=768, D=768. M_total = 32768.

typedef __attribute__((ext_vector_type(8))) short short8;   // 8 x bf16 (4 VGPRs)
typedef __attribute__((ext_vector_type(4))) short short4v;  // 4 x bf16 (8B)
typedef __attribute__((ext_vector_type(4))) float f32x4;

__device__ __forceinline__ short f2bf(float f) {
    uint32_t u = __float_as_uint(f);
    u += 0x7fffu + ((u >> 16) & 1u);   // RNE
    return (short)(u >> 16);
}

// ---------------------------------------------------------------------------
__global__ __launch_bounds__(256) void cvt_x(const float* __restrict__ x,
                                             short* __restrict__ xb) {
    long i = ((long)blockIdx.x * 256 + threadIdx.x) * 4;
    f32x4 v = *(const f32x4*)(x + i);
    short4v o;
    o.x = f2bf(v.x); o.y = f2bf(v.y); o.z = f2bf(v.z); o.w = f2bf(v.w);
    *(short4v*)(xb + i) = o;
}

// W [768,768] fp32 -> Wt [768,768] bf16 transposed
__global__ __launch_bounds__(256) void cvt_wt(const float* __restrict__ W,
                                              short* __restrict__ Wt) {
    __shared__ float tile[32][33];
    int d0 = blockIdx.x * 32, c0 = blockIdx.y * 32;
    int tr = threadIdx.x >> 5, tc = threadIdx.x & 31;
    #pragma unroll
    for (int i = 0; i < 32; i += 8)
        tile[tr + i][tc] = W[(long)(c0 + tr + i) * 768 + d0 + tc];
    __syncthreads();
    #pragma unroll
    for (int i = 0; i < 32; i += 8)
        Wt[(long)(d0 + tr + i) * 768 + c0 + tc] = f2bf(tile[tc][tr + i]);
}

// RoPE table: rt[t*384 + j] = (cos, sin)
__global__ __launch_bounds__(256) void rope_tab(float2* __restrict__ rt) {
    int i = blockIdx.x * 256 + threadIdx.x;   // 98304
    int t = i / 384, j = i - t * 384;
    const float CE = -0.034603417655f;        // -2*log2(10000)/768
    float th = exp2f((float)j * CE);
    float s, c;
    sincosf((float)t * th, &s, &c);
    rt[i] = make_float2(c, s);
}

// ---------------------------------------------------------------------------
// Fused QKV GEMM: 256x256 tile, BK=64, 8 waves (2Mx4N), 8-phase schedule with
// counted vmcnt (T3+T4), setprio around MFMA clusters (T5), rotation LDS
// swizzle (0 bank conflicts).
// C = A[32768x768] x B[2304x768]^T; epilogue: RoPE (q,k), transpose (v).
__global__ __launch_bounds__(512, 2)
void qkv256(const short* __restrict__ A, const short* __restrict__ B,
            short* __restrict__ Q, short* __restrict__ Kb,
            short* __restrict__ Vt, const float2* __restrict__ rt) {
    // grid 1152 flat = 8 XCDs x 16 M-stripes x 9 N-blocks (bijective)
    int p = blockIdx.x;
    int c = p & 7, j = p >> 3;          // j in [0,144)
    int st = j / 9;
    int bx = j - st * 9;                // [0,9)
    int by = c * 16 + st;               // [0,128)
    const int m0 = by * 256, n0 = bx * 256;

    __shared__ short lA[2][256 * 64];   // 64 KB
    __shared__ short lB[2][256 * 64];   // 64 KB

    const int tid = threadIdx.x;
    const int w = tid >> 6, lane = tid & 63;
    const int wm = (w >> 2) * 128;      // 2 M-waves
    const int wn = (w & 3) * 64;        // 4 N-waves
    const int lr8 = lane >> 3;
    const int scol = (((lane & 7) - lr8) & 7) * 8;  // rotation swizzle (stage)
    const int fr = lane & 15, kq = lane >> 4;

    f32x4 acc[8][4] = {};
    short8 af[4][2];
    short8 bq[4][2];

#define STAGE_HALF(lX, gX, r0g, h, t) do {                                     \
    int _buf = (t) & 1;                                                        \
    _Pragma("unroll")                                                          \
    for (int _i = 0; _i < 2; ++_i) {                                           \
        int _rl = (h) * 128 + (w * 2 + _i) * 8;                                \
        const short* _g = (gX) + (long)((r0g) + _rl + lr8) * 768               \
                               + (t) * 64 + scol;                              \
        __builtin_amdgcn_global_load_lds(                                      \
            (const __attribute__((address_space(1))) void*)_g,                 \
            (__attribute__((address_space(3))) void*)(&lX[_buf][_rl * 64]),    \
            16, 0, 0);                                                         \
    }                                                                          \
} while (0)

#define LOAD_A(mh, buf) do {                                                   \
    _Pragma("unroll")                                                          \
    for (int _t = 0; _t < 4; ++_t)                                             \
        _Pragma("unroll")                                                      \
        for (int _k = 0; _k < 2; ++_k)                                         \
            af[_t][_k] = *(const short8*)(&lA[buf][                            \
                (wm + (mh) * 64 + _t * 16 + fr) * 64 +                         \
                ((_k * 4 + kq + fr) & 7) * 8]);                                \
} while (0)

#define LOAD_B(nh, buf) do {                                                   \
    _Pragma("unroll")                                                          \
    for (int _t = 0; _t < 2; ++_t)                                             \
        _Pragma("unroll")                                                      \
        for (int _k = 0; _k < 2; ++_k)                                         \
            bq[(nh) * 2 + _t][_k] = *(const short8*)(&lB[buf][                 \
                (wn + (nh) * 32 + _t * 16 + fr) * 64 +                         \
                ((_k * 4 + kq + fr) & 7) * 8]);                                \
} while (0)

#define MMA_Q(mh, nh) do {                                                     \
    __builtin_amdgcn_s_setprio(1);                                             \
    _Pragma("unroll")                                                          \
    for (int _t = 0; _t < 4; ++_t)                                             \
        _Pragma("unroll")                                                      \
        for (int _n = 0; _n < 2; ++_n)                                         \
            _Pragma("unroll")                                                  \
            for (int _k = 0; _k < 2; ++_k)                                     \
                acc[(mh) * 4 + _t][(nh) * 2 + _n] =                            \
                    __builtin_amdgcn_mfma_f32_16x16x32_bf16(                   \
                        af[_t][_k], bq[(nh) * 2 + _n][_k],                     \
                        acc[(mh) * 4 + _t][(nh) * 2 + _n], 0, 0, 0);           \
    __builtin_amdgcn_s_setprio(0);                                             \
} while (0)

#define BAR() __builtin_amdgcn_s_barrier()
#define LGKM0() asm volatile("s_waitcnt lgkmcnt(0)" ::: "memory")
#define VMC4() asm volatile("s_waitcnt vmcnt(4)" ::: "memory")
#define VMC0() asm volatile("s_waitcnt vmcnt(0)" ::: "memory")

    // prologue: T0 {B0,B1,A0,A1}, T1 {B0,B1}; confirm T0
    STAGE_HALF(lB, B, n0, 0, 0);
    STAGE_HALF(lB, B, n0, 1, 0);
    STAGE_HALF(lA, A, m0, 0, 0);
    STAGE_HALF(lA, A, m0, 1, 0);
    STAGE_HALF(lB, B, n0, 0, 1);
    STAGE_HALF(lB, B, n0, 1, 1);
    VMC4();
    BAR();

    #pragma unroll 1
    for (int i = 0; i < 6; ++i) {
        const int t0 = 2 * i;
        const bool more = (i < 5);
        // phase 1
        LOAD_A(0, 0); LOAD_B(0, 0);
        STAGE_HALF(lA, A, m0, 0, t0 + 1);
        BAR(); LGKM0(); MMA_Q(0, 0); BAR();
        // phase 2
        LOAD_B(1, 0);
        STAGE_HALF(lA, A, m0, 1, t0 + 1);
        BAR(); LGKM0(); MMA_Q(0, 1); BAR();
        // phase 3
        LOAD_A(1, 0);
        if (more) STAGE_HALF(lB, B, n0, 0, t0 + 2);
        BAR(); LGKM0(); MMA_Q(1, 1); BAR();
        // phase 4: held regs; confirm tile 2i+1 after MFMA
        if (more) STAGE_HALF(lB, B, n0, 1, t0 + 2);
        BAR(); LGKM0(); MMA_Q(1, 0);
        if (more) { VMC4(); } else { VMC0(); }
        BAR();
        // phase 5
        LOAD_A(0, 1); LOAD_B(0, 1);
        if (more) STAGE_HALF(lA, A, m0, 0, t0 + 2);
        BAR(); LGKM0(); MMA_Q(0, 0); BAR();
        // phase 6
        LOAD_B(1, 1);
        if (more) STAGE_HALF(lA, A, m0, 1, t0 + 2);
        BAR(); LGKM0(); MMA_Q(0, 1); BAR();
        // phase 7
        LOAD_A(1, 1);
        if (more) STAGE_HALF(lB, B, n0, 0, t0 + 3);
        BAR(); LGKM0(); MMA_Q(1, 1); BAR();
        // phase 8: confirm tile 2i+2 after MFMA
        if (more) STAGE_HALF(lB, B, n0, 1, t0 + 3);
        BAR(); LGKM0(); MMA_Q(1, 0);
        if (more) VMC4();
        BAR();
    }

    // ---- epilogue; C/D layout: col = lane&15, row = (lane>>4)*4 + r
    const int type = (bx >= 6) ? 2 : (bx >= 3 ? 1 : 0);
    const int nl0 = n0 - type * 768;
    const int r0 = wm + (lane >> 4) * 4;
    const int c0 = wn + (lane & 15);
    if (type < 2) {
        short* dst = (type == 0) ? Q : Kb;
        const int par = lane & 1;
        #pragma unroll
        for (int tmi = 0; tmi < 8; ++tmi)
            #pragma unroll
            for (int tni = 0; tni < 4; ++tni) {
                int col = nl0 + c0 + tni * 16;
                const float2* rtc = rt + (col >> 1);
                #pragma unroll
                for (int r = 0; r < 4; ++r) {
                    int row = m0 + r0 + tmi * 16 + r;
                    float val = acc[tmi][tni][r];
                    float pv = __shfl_xor(val, 1);
                    float2 cs = rtc[(row & 255) * 384];
                    float re = par ? pv : val;
                    float im = par ? val : pv;
                    float o = par ? (re * cs.y + im * cs.x)
                                  : (re * cs.x - im * cs.y);
                    dst[(long)row * 768 + col] = f2bf(o);
                }
            }
    } else {
        #pragma unroll
        for (int tmi = 0; tmi < 8; ++tmi)
            #pragma unroll
            for (int tni = 0; tni < 4; ++tni) {
                int col = nl0 + c0 + tni * 16;
                #pragma unroll
                for (int r = 0; r < 4; ++r) {
                    int row = m0 + r0 + tmi * 16 + r;
                    Vt[((long)(row >> 8) * 768 + col) * 256 + (row & 255)] =
                        f2bf(acc[tmi][tni][r]);
                }
            }
    }
#undef STAGE_HALF
#undef LOAD_A
#undef LOAD_B
#undef MMA_Q
#undef BAR
#undef LGKM0
#undef VMC4
#undef VMC0
}

// ---------------------------------------------------------------------------
// Fused attention tail v3: counted-vmcnt pipeline (T4).
// grid 512 = (XCD, batch, q-quarter), 256 threads (4 waves), 80 KB LDS ->
// 2 blocks/CU. Causal trim: block qh stages/computes k-cols < (qh+1)*64 (NC
// chunks), templated on NC so all acc indexing + vmcnt immediates are
// compile-time. QK work balanced: wave w owns col-tiles w*NC+tni, tni<NC.
// Pipeline per step: MFMA(buf) -> BAR -> stage(t+2 into buf) -> vmcnt(Ns)
// (drains tile t+1, keeps tile t+2 in flight) -> BAR. Never drains to 0 in
// the loop. Softmax barriers are lgkm-only so V prefetch rides through.
// PV waits are store-aware: 32 out-stores retire in-order on the same vmcnt
// queue, so boundary wait = 36, else 4.
// LDS (shorts): QK: A dbuf [0,8192) | B dbuf [8192,40960).
//   post-QK alias: P chunks [0,16384) | V dbuf [16384,32768) |
//   f32 scratch [32768,33792). Total 81920 B.
#define BARA() __builtin_amdgcn_s_barrier()
#define VMW(n) asm volatile("s_waitcnt vmcnt(%0)" :: "n"(n) : "memory")
#define LBAR() do { asm volatile("s_waitcnt lgkmcnt(0)" ::: "memory");         \
                    __builtin_amdgcn_s_barrier(); } while (0)
#define GLL(g, l) __builtin_amdgcn_global_load_lds(                            \
        (const __attribute__((address_space(1))) void*)(g),                    \
        (__attribute__((address_space(3))) void*)(l), 16, 0, 0)
#define AQK_STAGE(t) do { int _b = (t) & 1;                                    \
    _Pragma("unroll")                                                          \
    for (int _i = 0; _i < 2; ++_i) { int _s = _i * 4 + w;                      \
        GLL(Ab + (long)(_s * 8 + lr8) * 768 + (t) * 64 + scol,                 \
            smem + _b * 4096 + _s * 512); }                                    \
    _Pragma("unroll")                                                          \
    for (int _i = 0; _i < 2 * NC; ++_i) { int _s = _i * 4 + w;                 \
        GLL(Bb + (long)(_s * 8 + lr8) * 768 + (t) * 64 + scol,                 \
            smem + 8192 + _b * 16384 + _s * 512); } } while (0)
#define AV_STAGE(dc, kc, vb) do {                                              \
    _Pragma("unroll")                                                          \
    for (int _i = 0; _i < 4; ++_i) { int _s = _i * 4 + w;                      \
        GLL(Vb + (long)((dc) * 128 + _s * 8 + lr8) * 256 + (kc) * 64 + scol,   \
            smem + 16384 + (vb) * 8192 + _s * 512); } } while (0)

template <int NC>
__device__ __forceinline__ void attn_body(
    int bz, int qh, const short* __restrict__ Ab, const short* __restrict__ Bb,
    const short* __restrict__ Vb, float* __restrict__ out, float scale,
    short* smem, int w, int lane) {
    const int lr8 = lane >> 3;
    const int scol = (((lane & 7) - lr8) & 7) * 8;  // rotation swizzle
    const int fr = lane & 15, kq = lane >> 4;
    const int wNC = w * NC;

    f32x4 acc[4][NC] = {};

    // ---- phase 1: QK, counted-vmcnt 2-deep pipeline -------------------
    AQK_STAGE(0);
    AQK_STAGE(1);
    VMW(2 + 2 * NC);
    BARA();
    #pragma unroll 1
    for (int t = 0; t < 12; ++t) {
        const short* la = smem + (t & 1) * 4096;
        const short* lb = smem + 8192 + (t & 1) * 16384;
        #pragma unroll
        for (int cc = 0; cc < 2; ++cc) {
            const int sp = ((cc * 4 + kq + fr) & 7) * 8;
            short8 afr[4];
            #pragma unroll
            for (int tmi = 0; tmi < 4; ++tmi)
                afr[tmi] = *(const short8*)(la + (tmi * 16 + fr) * 64 + sp);
            #pragma unroll
            for (int tni = 0; tni < NC; ++tni) {
                short8 bfr = *(const short8*)(
                    lb + ((wNC + tni) * 16 + fr) * 64 + sp);
                #pragma unroll
                for (int tmi = 0; tmi < 4; ++tmi)
                    acc[tmi][tni] = __builtin_amdgcn_mfma_f32_16x16x32_bf16(
                        afr[tmi], bfr, acc[tmi][tni], 0, 0, 0);
            }
        }
        BARA();
        if (t < 10) { AQK_STAGE(t + 2); VMW(2 + 2 * NC); }
        else if (t == 10) { VMW(0); }
        BARA();
    }

    // V prefetch for PV rides under the softmax (both buffers free now)
    AV_STAGE(0, 0, 0);
    AV_STAGE(1 / NC, 1 % NC, 1);

    // ---- phase 2: exact causal softmax (rows 0..63 local) -------------
    const int r0 = kq * 4;
    float* redm = (float*)(smem + 32768);   // [64][4]
    float* reds = redm + 256;               // [64][4]

    float M[16];
    #pragma unroll
    for (int tmi = 0; tmi < 4; ++tmi)
        #pragma unroll
        for (int r = 0; r < 4; ++r) {
            int rowL = tmi * 16 + r0 + r;
            int tloc = qh * 64 + rowL;
            float m = -1e30f;
            #pragma unroll
            for (int tni = 0; tni < NC; ++tni) {
                int col = (wNC + tni) * 16 + fr;
                float v = (col <= tloc) ? acc[tmi][tni][r] * scale : -1e30f;
                acc[tmi][tni][r] = v;
                m = fmaxf(m, v);
            }
            m = fmaxf(m, __shfl_xor(m, 1));
            m = fmaxf(m, __shfl_xor(m, 2));
            m = fmaxf(m, __shfl_xor(m, 4));
            m = fmaxf(m, __shfl_xor(m, 8));
            M[tmi * 4 + r] = m;
        }
    if (fr == 0) {
        #pragma unroll
        for (int tmi = 0; tmi < 4; ++tmi)
            #pragma unroll
            for (int r = 0; r < 4; ++r)
                redm[(tmi * 16 + r0 + r) * 4 + w] = M[tmi * 4 + r];
    }
    LBAR();
    #pragma unroll
    for (int tmi = 0; tmi < 4; ++tmi)
        #pragma unroll
        for (int r = 0; r < 4; ++r) {
            f32x4 v = *(const f32x4*)(redm + (tmi * 16 + r0 + r) * 4);
            M[tmi * 4 + r] = fmaxf(fmaxf(v.x, v.y), fmaxf(v.z, v.w));
        }
    float Sm[16];
    #pragma unroll
    for (int tmi = 0; tmi < 4; ++tmi)
        #pragma unroll
        for (int r = 0; r < 4; ++r) {
            float mm = M[tmi * 4 + r];
            float s = 0.f;
            #pragma unroll
            for (int tni = 0; tni < NC; ++tni) {
                float e = __expf(acc[tmi][tni][r] - mm);
                acc[tmi][tni][r] = e;
                s += e;
            }
            s += __shfl_xor(s, 1);
            s += __shfl_xor(s, 2);
            s += __shfl_xor(s, 4);
            s += __shfl_xor(s, 8);
            Sm[tmi * 4 + r] = s;
        }
    if (fr == 0) {
        #pragma unroll
        for (int tmi = 0; tmi < 4; ++tmi)
            #pragma unroll
            for (int r = 0; r < 4; ++r)
                reds[(tmi * 16 + r0 + r) * 4 + w] = Sm[tmi * 4 + r];
    }
    LBAR();

    // normalize + write P into LDS (bf16, rotation-swizzled fragment layout)
    // wave w owns col-tiles ct = wNC+tni: chunk = ct>>2, in-chunk pos = ct&3
    #pragma unroll
    for (int tmi = 0; tmi < 4; ++tmi)
        #pragma unroll
        for (int r = 0; r < 4; ++r) {
            int rowL = tmi * 16 + r0 + r;
            f32x4 sv = *(const f32x4*)(reds + rowL * 4);
            float inv = 1.0f / (sv.x + sv.y + sv.z + sv.w);
            #pragma unroll
            for (int tni = 0; tni < NC; ++tni) {
                int ct = wNC + tni;
                int l = (ct & 3) * 2 + (fr >> 3);      // logical 8-short slot
                smem[(ct >> 2) * 4096 + rowL * 64 +
                     ((l + rowL) & 7) * 8 + (fr & 7)] =
                    f2bf(acc[tmi][tni][r] * inv);
            }
        }
    asm volatile("s_waitcnt lgkmcnt(0)" ::: "memory");
    VMW(4);        // V(0) ready; V(1) stays in flight
    BARA();

    // ---- phase 3: PV, counted-vmcnt 2-deep pipeline -------------------
    const long rowB = (long)bz * 256 + (long)qh * 64;
    int s = 0;
    #pragma unroll 1
    for (int dc = 0; dc < 6; ++dc) {
        f32x4 a2[4][2] = {};
        #pragma unroll 1
        for (int kc = 0; kc < NC; ++kc, ++s) {
            const short* pch = smem + kc * 4096;
            const short* lv = smem + 16384 + (s & 1) * 8192;
            #pragma unroll
            for (int cc = 0; cc < 2; ++cc) {
                const int sp = ((cc * 4 + kq + fr) & 7) * 8;
                short8 ap[4], bv[2];
                #pragma unroll
                for (int tmi = 0; tmi < 4; ++tmi)
                    ap[tmi] = *(const short8*)(pch + (tmi * 16 + fr) * 64 + sp);
                #pragma unroll
                for (int tn = 0; tn < 2; ++tn)
                    bv[tn] = *(const short8*)(lv + (w * 32 + tn * 16 + fr) * 64 + sp);
                #pragma unroll
                for (int tmi = 0; tmi < 4; ++tmi)
                    #pragma unroll
                    for (int tn = 0; tn < 2; ++tn)
                        a2[tmi][tn] = __builtin_amdgcn_mfma_f32_16x16x32_bf16(
                            ap[tmi], bv[tn], a2[tmi][tn], 0, 0, 0);
            }
            const bool stq = (kc == NC - 1);
            if (stq) {   // store out chunk [64 q][128 d], fp32 (32 stores)
                #pragma unroll
                for (int tmi = 0; tmi < 4; ++tmi)
                    #pragma unroll
                    for (int tn = 0; tn < 2; ++tn)
                        #pragma unroll
                        for (int r = 0; r < 4; ++r) {
                            long row = rowB + tmi * 16 + kq * 4 + r;
                            int col = dc * 128 + w * 32 + tn * 16 + fr;
                            out[row * 768 + col] = a2[tmi][tn][r];
                        }
            }
            BARA();
            const int s2 = s + 2;
            const bool pre = (s2 < 6 * NC);
            if (pre) AV_STAGE(s2 / NC, s2 % NC, s & 1);
            if (stq && pre)      VMW(36);
            else if (stq)        VMW(32);
            else if (pre)        VMW(4);
            else                 VMW(0);
            BARA();
        }
    }
}

__global__ __launch_bounds__(256)
void attn3(const short* __restrict__ Qm, const short* __restrict__ Km,
           const short* __restrict__ Vm, float* __restrict__ out,
           float scale) {
    __shared__ short smem[40960];       // 80 KB -> 2 blocks/CU
    int p = blockIdx.x;
    int c = p & 7, j = p >> 3;          // j in [0,64)
    int b = j >> 2, q0 = j & 3;
    int qh = (b & 8) ? 3 - q0 : q0;     // heavy/light pairing across CU rounds
    int bz = c * 16 + b;
    const short* Ab = Qm + (long)bz * 196608 + (long)qh * 49152;  // 64 q-rows
    const short* Bb = Km + (long)bz * 196608;
    const short* Vb = Vm + (long)bz * 196608;   // vt[batch][768 d][256 t]
    int w = threadIdx.x >> 6, lane = threadIdx.x & 63;
    switch (qh) {
        case 0:  attn_body<1>(bz, qh, Ab, Bb, Vb, out, scale, smem, w, lane); break;
        case 1:  attn_body<2>(bz, qh, Ab, Bb, Vb, out, scale, smem, w, lane); break;
        case 2:  attn_body<3>(bz, qh, Ab, Bb, Vb, out, scale, smem, w, lane); break;
        default: attn_body<4>(bz, qh, Ab, Bb, Vb, out, scale, smem, w, lane); break;
    }
}
#undef BARA
#undef VMW
#undef LBAR
#undef GLL
#undef AQK_STAGE
#undef AV_STAGE

// ---------------------------------------------------------------------------
extern "C" void kernel_launch(void* const* d_in, const int* in_sizes, int n_in,
                              void* d_out, int out_size, void* d_ws, size_t ws_size,
                              hipStream_t stream) {
    const float* x  = (const float*)d_in[0];
    const float* Wq = (const float*)d_in[1];
    const float* Wk = (const float*)d_in[2];
    const float* Wv = (const float*)d_in[3];

    char* ws = (char*)d_ws;
    short*  xb = (short*)(ws);                   // 48 MB   x bf16
    short*  wt = (short*)(ws + 50331648);        // 3.375MB Wqkv^T bf16 [2304,768]
    short*  qb = (short*)(ws + 53870592);        // 48 MB   q bf16 (roped)
    short*  kb = (short*)(ws + 104202240);       // 48 MB   k bf16 (roped)
    short*  vt = (short*)(ws + 154533888);       // 48 MB   v^T bf16 [128][768][256]
    float2* rt = (float2*)(ws + 255197184);      // 768 KB  rope table

    cvt_x<<<24576, 256, 0, stream>>>(x, xb);
    dim3 gw(24, 24);
    cvt_wt<<<gw, 256, 0, stream>>>(Wq, wt);
    cvt_wt<<<gw, 256, 0, stream>>>(Wk, wt + 589824);
    cvt_wt<<<gw, 256, 0, stream>>>(Wv, wt + 1179648);
    rope_tab<<<384, 256, 0, stream>>>(rt);

    // Fused QKV: [32768,768] x [2304,768]^T, 256^2 8-phase, RoPE/v-T epilogue
    qkv256<<<1152, 512, 0, stream>>>(xb, wt, qb, kb, vt, rt);

    // Fused attention tail v3: counted-vmcnt pipeline, 2 blocks/CU
    attn3<<<512, 256, 0, stream>>>(qb, kb, vt, (float*)d_out, 0.0360843918f);
}

// Round 6
// 410.676 us; speedup vs baseline: 1.0046x; 1.0046x over previous
//
#include <hip/hip_runtime.h>
#include <hip/hip_bf16.h>
#include <stdint.h>

// B=128, T=256, C=768, D=768. M_total = 32768.

typedef __attribute__((ext_vector_type(8))) short short8;   // 8 x bf16 (4 VGPRs)
typedef __attribute__((ext_vector_type(4))) short short4v;  // 4 x bf16 (8B)
typedef __attribute__((ext_vector_type(4))) float f32x4;

__device__ __forceinline__ short f2bf(float f) {
    uint32_t u = __float_as_uint(f);
    u += 0x7fffu + ((u >> 16) & 1u);   // RNE
    return (short)(u >> 16);
}

// ---------------------------------------------------------------------------
__global__ __launch_bounds__(256) void cvt_x(const float* __restrict__ x,
                                             short* __restrict__ xb) {
    long i = ((long)blockIdx.x * 256 + threadIdx.x) * 4;
    f32x4 v = *(const f32x4*)(x + i);
    short4v o;
    o.x = f2bf(v.x); o.y = f2bf(v.y); o.z = f2bf(v.z); o.w = f2bf(v.w);
    *(short4v*)(xb + i) = o;
}

// W [768,768] fp32 -> Wt [768,768] bf16 transposed
__global__ __launch_bounds__(256) void cvt_wt(const float* __restrict__ W,
                                              short* __restrict__ Wt) {
    __shared__ float tile[32][33];
    int d0 = blockIdx.x * 32, c0 = blockIdx.y * 32;
    int tr = threadIdx.x >> 5, tc = threadIdx.x & 31;
    #pragma unroll
    for (int i = 0; i < 32; i += 8)
        tile[tr + i][tc] = W[(long)(c0 + tr + i) * 768 + d0 + tc];
    __syncthreads();
    #pragma unroll
    for (int i = 0; i < 32; i += 8)
        Wt[(long)(d0 + tr + i) * 768 + c0 + tc] = f2bf(tile[tc][tr + i]);
}

// RoPE table: rt[t*384 + j] = (cos, sin)
__global__ __launch_bounds__(256) void rope_tab(float2* __restrict__ rt) {
    int i = blockIdx.x * 256 + threadIdx.x;   // 98304
    int t = i / 384, j = i - t * 384;
    const float CE = -0.034603417655f;        // -2*log2(10000)/768
    float th = exp2f((float)j * CE);
    float s, c;
    sincosf((float)t * th, &s, &c);
    rt[i] = make_float2(c, s);
}

// ---------------------------------------------------------------------------
// Fused QKV GEMM: 256x256 tile, BK=64, 8 waves (2Mx4N), 8-phase schedule with
// counted vmcnt (T3+T4), setprio around MFMA clusters (T5), rotation LDS
// swizzle (0 bank conflicts).
// C = A[32768x768] x B[2304x768]^T; epilogue: RoPE (q,k), transpose (v).
__global__ __launch_bounds__(512, 2)
void qkv256(const short* __restrict__ A, const short* __restrict__ B,
            short* __restrict__ Q, short* __restrict__ Kb,
            short* __restrict__ Vt, const float2* __restrict__ rt) {
    // grid 1152 flat = 8 XCDs x 16 M-stripes x 9 N-blocks (bijective)
    int p = blockIdx.x;
    int c = p & 7, j = p >> 3;          // j in [0,144)
    int st = j / 9;
    int bx = j - st * 9;                // [0,9)
    int by = c * 16 + st;               // [0,128)
    const int m0 = by * 256, n0 = bx * 256;

    __shared__ short lA[2][256 * 64];   // 64 KB
    __shared__ short lB[2][256 * 64];   // 64 KB

    const int tid = threadIdx.x;
    const int w = tid >> 6, lane = tid & 63;
    const int wm = (w >> 2) * 128;      // 2 M-waves
    const int wn = (w & 3) * 64;        // 4 N-waves
    const int lr8 = lane >> 3;
    const int scol = (((lane & 7) - lr8) & 7) * 8;  // rotation swizzle (stage)
    const int fr = lane & 15, kq = lane >> 4;

    f32x4 acc[8][4] = {};
    short8 af[4][2];
    short8 bq[4][2];

#define STAGE_HALF(lX, gX, r0g, h, t) do {                                     \
    int _buf = (t) & 1;                                                        \
    _Pragma("unroll")                                                          \
    for (int _i = 0; _i < 2; ++_i) {                                           \
        int _rl = (h) * 128 + (w * 2 + _i) * 8;                                \
        const short* _g = (gX) + (long)((r0g) + _rl + lr8) * 768               \
                               + (t) * 64 + scol;                              \
        __builtin_amdgcn_global_load_lds(                                      \
            (const __attribute__((address_space(1))) void*)_g,                 \
            (__attribute__((address_space(3))) void*)(&lX[_buf][_rl * 64]),    \
            16, 0, 0);                                                         \
    }                                                                          \
} while (0)

#define LOAD_A(mh, buf) do {                                                   \
    _Pragma("unroll")                                                          \
    for (int _t = 0; _t < 4; ++_t)                                             \
        _Pragma("unroll")                                                      \
        for (int _k = 0; _k < 2; ++_k)                                         \
            af[_t][_k] = *(const short8*)(&lA[buf][                            \
                (wm + (mh) * 64 + _t * 16 + fr) * 64 +                         \
                ((_k * 4 + kq + fr) & 7) * 8]);                                \
} while (0)

#define LOAD_B(nh, buf) do {                                                   \
    _Pragma("unroll")                                                          \
    for (int _t = 0; _t < 2; ++_t)                                             \
        _Pragma("unroll")                                                      \
        for (int _k = 0; _k < 2; ++_k)                                         \
            bq[(nh) * 2 + _t][_k] = *(const short8*)(&lB[buf][                 \
                (wn + (nh) * 32 + _t * 16 + fr) * 64 +                         \
                ((_k * 4 + kq + fr) & 7) * 8]);                                \
} while (0)

#define MMA_Q(mh, nh) do {                                                     \
    __builtin_amdgcn_s_setprio(1);                                             \
    _Pragma("unroll")                                                          \
    for (int _t = 0; _t < 4; ++_t)                                             \
        _Pragma("unroll")                                                      \
        for (int _n = 0; _n < 2; ++_n)                                         \
            _Pragma("unroll")                                                  \
            for (int _k = 0; _k < 2; ++_k)                                     \
                acc[(mh) * 4 + _t][(nh) * 2 + _n] =                            \
                    __builtin_amdgcn_mfma_f32_16x16x32_bf16(                   \
                        af[_t][_k], bq[(nh) * 2 + _n][_k],                     \
                        acc[(mh) * 4 + _t][(nh) * 2 + _n], 0, 0, 0);           \
    __builtin_amdgcn_s_setprio(0);                                             \
} while (0)

#define BAR() __builtin_amdgcn_s_barrier()
#define LGKM0() asm volatile("s_waitcnt lgkmcnt(0)" ::: "memory")
#define VMC4() asm volatile("s_waitcnt vmcnt(4)" ::: "memory")
#define VMC0() asm volatile("s_waitcnt vmcnt(0)" ::: "memory")

    // prologue: T0 {B0,B1,A0,A1}, T1 {B0,B1}; confirm T0
    STAGE_HALF(lB, B, n0, 0, 0);
    STAGE_HALF(lB, B, n0, 1, 0);
    STAGE_HALF(lA, A, m0, 0, 0);
    STAGE_HALF(lA, A, m0, 1, 0);
    STAGE_HALF(lB, B, n0, 0, 1);
    STAGE_HALF(lB, B, n0, 1, 1);
    VMC4();
    BAR();

    #pragma unroll 1
    for (int i = 0; i < 6; ++i) {
        const int t0 = 2 * i;
        const bool more = (i < 5);
        // phase 1
        LOAD_A(0, 0); LOAD_B(0, 0);
        STAGE_HALF(lA, A, m0, 0, t0 + 1);
        BAR(); LGKM0(); MMA_Q(0, 0); BAR();
        // phase 2
        LOAD_B(1, 0);
        STAGE_HALF(lA, A, m0, 1, t0 + 1);
        BAR(); LGKM0(); MMA_Q(0, 1); BAR();
        // phase 3
        LOAD_A(1, 0);
        if (more) STAGE_HALF(lB, B, n0, 0, t0 + 2);
        BAR(); LGKM0(); MMA_Q(1, 1); BAR();
        // phase 4: held regs; confirm tile 2i+1 after MFMA
        if (more) STAGE_HALF(lB, B, n0, 1, t0 + 2);
        BAR(); LGKM0(); MMA_Q(1, 0);
        if (more) { VMC4(); } else { VMC0(); }
        BAR();
        // phase 5
        LOAD_A(0, 1); LOAD_B(0, 1);
        if (more) STAGE_HALF(lA, A, m0, 0, t0 + 2);
        BAR(); LGKM0(); MMA_Q(0, 0); BAR();
        // phase 6
        LOAD_B(1, 1);
        if (more) STAGE_HALF(lA, A, m0, 1, t0 + 2);
        BAR(); LGKM0(); MMA_Q(0, 1); BAR();
        // phase 7
        LOAD_A(1, 1);
        if (more) STAGE_HALF(lB, B, n0, 0, t0 + 3);
        BAR(); LGKM0(); MMA_Q(1, 1); BAR();
        // phase 8: confirm tile 2i+2 after MFMA
        if (more) STAGE_HALF(lB, B, n0, 1, t0 + 3);
        BAR(); LGKM0(); MMA_Q(1, 0);
        if (more) VMC4();
        BAR();
    }

    // ---- epilogue; C/D layout: col = lane&15, row = (lane>>4)*4 + r
    const int type = (bx >= 6) ? 2 : (bx >= 3 ? 1 : 0);
    const int nl0 = n0 - type * 768;
    const int r0 = wm + (lane >> 4) * 4;
    const int c0 = wn + (lane & 15);
    if (type < 2) {
        short* dst = (type == 0) ? Q : Kb;
        const int par = lane & 1;
        #pragma unroll
        for (int tmi = 0; tmi < 8; ++tmi)
            #pragma unroll
            for (int tni = 0; tni < 4; ++tni) {
                int col = nl0 + c0 + tni * 16;
                const float2* rtc = rt + (col >> 1);
                #pragma unroll
                for (int r = 0; r < 4; ++r) {
                    int row = m0 + r0 + tmi * 16 + r;
                    float val = acc[tmi][tni][r];
                    float pv = __shfl_xor(val, 1);
                    float2 cs = rtc[(row & 255) * 384];
                    float re = par ? pv : val;
                    float im = par ? val : pv;
                    float o = par ? (re * cs.y + im * cs.x)
                                  : (re * cs.x - im * cs.y);
                    dst[(long)row * 768 + col] = f2bf(o);
                }
            }
    } else {
        #pragma unroll
        for (int tmi = 0; tmi < 8; ++tmi)
            #pragma unroll
            for (int tni = 0; tni < 4; ++tni) {
                int col = nl0 + c0 + tni * 16;
                #pragma unroll
                for (int r = 0; r < 4; ++r) {
                    int row = m0 + r0 + tmi * 16 + r;
                    Vt[((long)(row >> 8) * 768 + col) * 256 + (row & 255)] =
                        f2bf(acc[tmi][tni][r]);
                }
            }
    }
#undef STAGE_HALF
#undef LOAD_A
#undef LOAD_B
#undef MMA_Q
#undef BAR
#undef LGKM0
#undef VMC4
#undef VMC0
}

// ---------------------------------------------------------------------------
// Fused attention tail v4: register-direct MFMA operands, no staging barriers.
// Insight: kb [t][d] and vt [d][t] are already laid out so that one MFMA
// B-fragment = one contiguous 16B load per lane (row = lane&15, k = (lane>>4)*8
// -- identical to the fragment the LDS path read). So Q/K/V never touch LDS:
// fragments load global->VGPR with 2-slice prefetch; the compiler emits
// counted vmcnt waits per-wave; waves run barrier-free through both GEMM
// phases. LDS only holds P (transpose via verified rotation swizzle) +
// softmax scratch = 34 KB. __launch_bounds__(256,3) -> 12 waves/CU.
// Grid 512 = (XCD, batch, q-quarter); template NC = causal 64-col chunks.
// Accumulation order (k ascending; t ascending) identical to v3 -> bitwise
// same output.
#define LBAR() do { asm volatile("s_waitcnt lgkmcnt(0)" ::: "memory");         \
                    __builtin_amdgcn_s_barrier(); } while (0)

template <int NC>
__device__ __forceinline__ void attn_core(
    int bz, int qh, const short* __restrict__ qb, const short* __restrict__ kb,
    const short* __restrict__ vt, float* __restrict__ out, float scale,
    short* smem, int w, int lane) {
    const int fr = lane & 15, kq = lane >> 4;
    const int wNC = w * NC;
    const short* Aq = qb + ((long)bz * 256 + qh * 64) * 768;
    const short* Bk = kb + (long)bz * 196608;
    const short* Vv = vt + (long)bz * 196608;   // [768 d][256 t]

    f32x4 acc[4][NC];
    #pragma unroll
    for (int m = 0; m < 4; ++m)
        #pragma unroll
        for (int n = 0; n < NC; ++n) acc[m][n] = (f32x4){0.f, 0.f, 0.f, 0.f};

    short8 a0[4], a1[4], b0[NC], b1[NC];

#define LDQ(ab, bb, ks) do {                                                   \
    _Pragma("unroll")                                                          \
    for (int _m = 0; _m < 4; ++_m)                                             \
        ab[_m] = *(const short8*)(Aq + (long)(_m * 16 + fr) * 768              \
                                  + (ks) * 32 + kq * 8);                       \
    _Pragma("unroll")                                                          \
    for (int _n = 0; _n < NC; ++_n)                                            \
        bb[_n] = *(const short8*)(Bk + (long)((wNC + _n) * 16 + fr) * 768      \
                                  + (ks) * 32 + kq * 8);                       \
} while (0)
#define MMQ(ab, bb) do {                                                       \
    _Pragma("unroll")                                                          \
    for (int _m = 0; _m < 4; ++_m)                                             \
        _Pragma("unroll")                                                      \
        for (int _n = 0; _n < NC; ++_n)                                        \
            acc[_m][_n] = __builtin_amdgcn_mfma_f32_16x16x32_bf16(             \
                ab[_m], bb[_n], acc[_m][_n], 0, 0, 0);                         \
} while (0)

    // ---- phase 1: QK^T, barrier-free, 2-slice reg prefetch ------------
    LDQ(a0, b0, 0);
    LDQ(a1, b1, 1);
    #pragma unroll 1
    for (int ks = 0; ks < 24; ks += 2) {
        MMQ(a0, b0);
        if (ks < 22) LDQ(a0, b0, ks + 2);
        MMQ(a1, b1);
        if (ks < 22) LDQ(a1, b1, ks + 3);
    }

    // ---- phase 2: exact causal softmax (rows 0..63 local) -------------
    const int r0 = kq * 4;
    float* redm = (float*)(smem + 16384);   // [64][4]
    float* reds = redm + 256;               // [64][4]

    float M[16];
    #pragma unroll
    for (int tmi = 0; tmi < 4; ++tmi)
        #pragma unroll
        for (int r = 0; r < 4; ++r) {
            int rowL = tmi * 16 + r0 + r;
            int tloc = qh * 64 + rowL;
            float m = -1e30f;
            #pragma unroll
            for (int tni = 0; tni < NC; ++tni) {
                int col = (wNC + tni) * 16 + fr;
                float v = (col <= tloc) ? acc[tmi][tni][r] * scale : -1e30f;
                acc[tmi][tni][r] = v;
                m = fmaxf(m, v);
            }
            m = fmaxf(m, __shfl_xor(m, 1));
            m = fmaxf(m, __shfl_xor(m, 2));
            m = fmaxf(m, __shfl_xor(m, 4));
            m = fmaxf(m, __shfl_xor(m, 8));
            M[tmi * 4 + r] = m;
        }
    if (fr == 0) {
        #pragma unroll
        for (int tmi = 0; tmi < 4; ++tmi)
            #pragma unroll
            for (int r = 0; r < 4; ++r)
                redm[(tmi * 16 + r0 + r) * 4 + w] = M[tmi * 4 + r];
    }
    LBAR();
    #pragma unroll
    for (int tmi = 0; tmi < 4; ++tmi)
        #pragma unroll
        for (int r = 0; r < 4; ++r) {
            f32x4 v = *(const f32x4*)(redm + (tmi * 16 + r0 + r) * 4);
            M[tmi * 4 + r] = fmaxf(fmaxf(v.x, v.y), fmaxf(v.z, v.w));
        }
    float Sm[16];
    #pragma unroll
    for (int tmi = 0; tmi < 4; ++tmi)
        #pragma unroll
        for (int r = 0; r < 4; ++r) {
            float mm = M[tmi * 4 + r];
            float s = 0.f;
            #pragma unroll
            for (int tni = 0; tni < NC; ++tni) {
                float e = __expf(acc[tmi][tni][r] - mm);
                acc[tmi][tni][r] = e;
                s += e;
            }
            s += __shfl_xor(s, 1);
            s += __shfl_xor(s, 2);
            s += __shfl_xor(s, 4);
            s += __shfl_xor(s, 8);
            Sm[tmi * 4 + r] = s;
        }
    if (fr == 0) {
        #pragma unroll
        for (int tmi = 0; tmi < 4; ++tmi)
            #pragma unroll
            for (int r = 0; r < 4; ++r)
                reds[(tmi * 16 + r0 + r) * 4 + w] = Sm[tmi * 4 + r];
    }
    LBAR();

    // V slice-0 prefetch rides under normalize + P-write + barrier
    short8 v0[2], v1[2];
#define LDV(vb, s) do {                                                        \
    int _dc = (s) / (2 * NC), _ts = (s) - _dc * 2 * NC;                        \
    _Pragma("unroll")                                                          \
    for (int _tn = 0; _tn < 2; ++_tn)                                          \
        vb[_tn] = *(const short8*)(Vv +                                        \
            (long)(_dc * 128 + w * 32 + _tn * 16 + fr) * 256                   \
            + _ts * 32 + kq * 8);                                              \
} while (0)
    LDV(v0, 0);

    // normalize + write P into LDS (bf16, rotation-swizzled fragment layout)
    // wave w owns col-tiles ct = wNC+tni: chunk = ct>>2, in-chunk pos = ct&3
    #pragma unroll
    for (int tmi = 0; tmi < 4; ++tmi)
        #pragma unroll
        for (int r = 0; r < 4; ++r) {
            int rowL = tmi * 16 + r0 + r;
            f32x4 sv = *(const f32x4*)(reds + rowL * 4);
            float inv = 1.0f / (sv.x + sv.y + sv.z + sv.w);
            #pragma unroll
            for (int tni = 0; tni < NC; ++tni) {
                int ct = wNC + tni;
                int l = (ct & 3) * 2 + (fr >> 3);      // logical 8-short slot
                smem[(ct >> 2) * 4096 + rowL * 64 +
                     ((l + rowL) & 7) * 8 + (fr & 7)] =
                    f2bf(acc[tmi][tni][r] * inv);
            }
        }
    LBAR();   // P visible (lgkm-only: V prefetch keeps flying)

    // ---- phase 3: PV, barrier-free, 2-slice reg prefetch of V ---------
    // slice s: dc = s/(2NC), ts = s%(2NC); P chunk kc = ts>>1, half cc = ts&1
    f32x4 a2[4][2] = {};
    const long rowB = (long)bz * 256 + (long)qh * 64;
#define MMP(vb, s) do {                                                        \
    int _dc2 = (s) / (2 * NC), _ts2 = (s) - _dc2 * 2 * NC;                     \
    int _kc = _ts2 >> 1, _cc = _ts2 & 1;                                       \
    const short* _p = smem + _kc * 4096;                                       \
    const int _sp = ((_cc * 4 + kq + fr) & 7) * 8;                             \
    _Pragma("unroll")                                                          \
    for (int _m = 0; _m < 4; ++_m) {                                           \
        short8 _ap = *(const short8*)(_p + (_m * 16 + fr) * 64 + _sp);         \
        _Pragma("unroll")                                                      \
        for (int _tn = 0; _tn < 2; ++_tn)                                      \
            a2[_m][_tn] = __builtin_amdgcn_mfma_f32_16x16x32_bf16(             \
                _ap, vb[_tn], a2[_m][_tn], 0, 0, 0);                           \
    }                                                                          \
} while (0)
#define STO(dcv) do {                                                          \
    _Pragma("unroll")                                                          \
    for (int _m = 0; _m < 4; ++_m)                                             \
        _Pragma("unroll")                                                      \
        for (int _tn = 0; _tn < 2; ++_tn)                                      \
            _Pragma("unroll")                                                  \
            for (int _r = 0; _r < 4; ++_r) {                                   \
                long _row = rowB + _m * 16 + kq * 4 + _r;                      \
                int _col = (dcv) * 128 + w * 32 + _tn * 16 + fr;               \
                out[_row * 768 + _col] = a2[_m][_tn][_r];                      \
            }                                                                  \
    _Pragma("unroll")                                                          \
    for (int _m = 0; _m < 4; ++_m)                                             \
        _Pragma("unroll")                                                      \
        for (int _tn = 0; _tn < 2; ++_tn)                                      \
            a2[_m][_tn] = (f32x4){0.f, 0.f, 0.f, 0.f};                         \
} while (0)

    LDV(v1, 1);
    #pragma unroll 1
    for (int s = 0; s < 12 * NC; s += 2) {
        MMP(v0, s);
        if (s + 2 < 12 * NC) LDV(v0, s + 2);
        MMP(v1, s + 1);
        if (s + 3 < 12 * NC) LDV(v1, s + 3);
        if (((s + 2) % (2 * NC)) == 0) STO((s + 1) / (2 * NC));
    }
#undef LDQ
#undef MMQ
#undef LDV
#undef MMP
#undef STO
}

__global__ __launch_bounds__(256, 3)
void attn4(const short* __restrict__ Qm, const short* __restrict__ Km,
           const short* __restrict__ Vm, float* __restrict__ out,
           float scale) {
    __shared__ short smem[17408];       // 34 KB: P(32K) + f32 scratch(2K)
    int p = blockIdx.x;
    int c = p & 7, j = p >> 3;          // j in [0,64)
    int b = j >> 2, q0 = j & 3;
    int qh = (b & 8) ? 3 - q0 : q0;     // heavy/light pairing across rounds
    int bz = c * 16 + b;
    int w = threadIdx.x >> 6, lane = threadIdx.x & 63;
    switch (qh) {
        case 0:  attn_core<1>(bz, qh, Qm, Km, Vm, out, scale, smem, w, lane); break;
        case 1:  attn_core<2>(bz, qh, Qm, Km, Vm, out, scale, smem, w, lane); break;
        case 2:  attn_core<3>(bz, qh, Qm, Km, Vm, out, scale, smem, w, lane); break;
        default: attn_core<4>(bz, qh, Qm, Km, Vm, out, scale, smem, w, lane); break;
    }
}
#undef LBAR

// ---------------------------------------------------------------------------
extern "C" void kernel_launch(void* const* d_in, const int* in_sizes, int n_in,
                              void* d_out, int out_size, void* d_ws, size_t ws_size,
                              hipStream_t stream) {
    const float* x  = (const float*)d_in[0];
    const float* Wq = (const float*)d_in[1];
    const float* Wk = (const float*)d_in[2];
    const float* Wv = (const float*)d_in[3];

    char* ws = (char*)d_ws;
    short*  xb = (short*)(ws);                   // 48 MB   x bf16
    short*  wt = (short*)(ws + 50331648);        // 3.375MB Wqkv^T bf16 [2304,768]
    short*  qb = (short*)(ws + 53870592);        // 48 MB   q bf16 (roped)
    short*  kb = (short*)(ws + 104202240);       // 48 MB   k bf16 (roped)
    short*  vt = (short*)(ws + 154533888);       // 48 MB   v^T bf16 [128][768][256]
    float2* rt = (float2*)(ws + 255197184);      // 768 KB  rope table

    cvt_x<<<24576, 256, 0, stream>>>(x, xb);
    dim3 gw(24, 24);
    cvt_wt<<<gw, 256, 0, stream>>>(Wq, wt);
    cvt_wt<<<gw, 256, 0, stream>>>(Wk, wt + 589824);
    cvt_wt<<<gw, 256, 0, stream>>>(Wv, wt + 1179648);
    rope_tab<<<384, 256, 0, stream>>>(rt);

    // Fused QKV: [32768,768] x [2304,768]^T, 256^2 8-phase, RoPE/v-T epilogue
    qkv256<<<1152, 512, 0, stream>>>(xb, wt, qb, kb, vt, rt);

    // Fused attention tail v4: register-direct operands, barrier-free GEMMs
    attn4<<<512, 256, 0, stream>>>(qb, kb, vt, (float*)d_out, 0.0360843918f);
}